// Round 5
// baseline (242.823 us; speedup 1.0000x reference)
//
#include <hip/hip_runtime.h>
#include <hip/hip_fp16.h>
#include <hip/hip_cooperative_groups.h>

namespace cg = cooperative_groups;

// DenseMultiRangeAttention on MI355X (gfx950) — round 5: cooperative fused
// kernel, 256 blocks (co-residency guaranteed), with return-code-checked
// fallback to the proven 4-kernel path.
// B=2, C=96, H=W=64, heads=4, d=24, ranges {7,9,11}.

#define HW    4096
#define NH    4
#define D     24
#define CC    96
#define C3    288
#define BATCH 2

#define TS    8
#define HALO  5
#define SW    18
#define SPIX  324      // SW*SW
#define PSTR  24       // u16 per staged K/V pixel = 48B
#define PBS   25       // partial stride (f32): l + 24 acc; gcd(25,32)=1

#define INV_SCALE 0.20412414523193151f  // 1/sqrt(24)

typedef unsigned short u16;
typedef _Float16 h2f __attribute__((ext_vector_type(2)));

__device__ __forceinline__ float fdot2h(unsigned int a, unsigned int b, float c) {
#if __has_builtin(__builtin_amdgcn_fdot2)
    return __builtin_amdgcn_fdot2(__builtin_bit_cast(h2f, a),
                                  __builtin_bit_cast(h2f, b), c, false);
#else
    float2 fa = __half22float2(__builtin_bit_cast(__half2, a));
    float2 fb = __half22float2(__builtin_bit_cast(__half2, b));
    return fmaf(fa.x, fb.x, fmaf(fa.y, fb.y, c));
#endif
}

__device__ __forceinline__ unsigned int packh2(float a, float b) {
    return __builtin_bit_cast(unsigned int, __floats2half2_rn(a, b));
}

// ======================= shared device helpers (used by both paths) =========

__device__ __forceinline__ void qkv_wave_task(
    int task, int lane, const float* __restrict__ x,
    const float* __restrict__ wq, const float* __restrict__ bq,
    const float* __restrict__ wk, const float* __restrict__ bk,
    const float* __restrict__ wv, const float* __restrict__ bv,
    u16* __restrict__ Qh, u16* __restrict__ Kh, u16* __restrict__ Vh)
{
    // task = zm*512 + pxg*4 + tw ; zm = mat + 3*z
    int tw  = task & 3;
    int pxg = (task >> 2) & 127;
    int zm  = task >> 9;             // 0..5
    int mat = zm % 3;
    int z   = zm / 3;
    const float* w    = (mat == 0) ? wq : (mat == 1) ? wk : wv;
    const float* bias = (mat == 0) ? bq : (mat == 1) ? bk : bv;
    u16* dst          = (mat == 0) ? Qh : (mat == 1) ? Kh : Vh;

    int gp = pxg * 64 + lane;
    int b  = gp >> 12;
    int p  = gp & 4095;
    int o0 = z * 48 + tw * 12;
    const float* xb = x + (size_t)b * CC * HW + p;

    float acc[12];
    #pragma unroll
    for (int j = 0; j < 12; ++j) acc[j] = bias[o0 + j];

    #pragma unroll
    for (int cb = 0; cb < 6; ++cb) {
        float xc[16];
        #pragma unroll
        for (int i = 0; i < 16; ++i)
            xc[i] = xb[(size_t)(cb * 16 + i) * HW];
        #pragma unroll
        for (int j = 0; j < 12; ++j) {
            const float* wr = w + (o0 + j) * CC + cb * 16;
            #pragma unroll
            for (int i = 0; i < 16; ++i) acc[j] = fmaf(wr[i], xc[i], acc[j]);
        }
    }

    unsigned int u[6];
    #pragma unroll
    for (int i = 0; i < 6; ++i) u[i] = packh2(acc[2 * i], acc[2 * i + 1]);
    uint2* dp = (uint2*)(dst + (size_t)gp * CC + o0);
    dp[0] = make_uint2(u[0], u[1]);
    dp[1] = make_uint2(u[2], u[3]);
    dp[2] = make_uint2(u[4], u[5]);
}

// One attention tile (8x8 px, one (b,h)), 8 waves cooperate. LDS layout:
// [Ks 15552 | Vs 15552] during visits, aliased by Pb (8*64*25 f32 = 51200)
// for the partial combine. Caller must __syncthreads() before LDS reuse.
__device__ __forceinline__ void attn_tile(
    int tile, int t, int wvid, int lane, char* smem,
    const u16* __restrict__ Qh, const u16* __restrict__ Kh,
    const u16* __restrict__ Vh, u16* __restrict__ att)
{
    u16*   Ks = (u16*)smem;
    u16*   Vs = Ks + SPIX * PSTR;
    float* Pb = (float*)smem;

    int bh = tile >> 6;
    int b  = bh >> 2, h = bh & 3;
    int x0 = (tile & 7) * TS, y0 = ((tile >> 3) & 7) * TS;

    if (t < SPIX) {
        int sp = t;
        int sy = sp / SW, sx = sp - sy * SW;
        int gy = y0 + sy - HALO, gx = x0 + sx - HALO;
        uint4 k0 = make_uint4(0,0,0,0), k1 = k0, k2 = k0;
        uint4 v0 = k0, v1 = k0, v2 = k0;
        if ((unsigned)gy < 64u && (unsigned)gx < 64u) {
            size_t base = ((size_t)(b * HW + gy * 64 + gx) * CC + h * D);
            const uint4* ksrc = (const uint4*)(Kh + base);
            const uint4* vsrc = (const uint4*)(Vh + base);
            k0 = ksrc[0]; k1 = ksrc[1]; k2 = ksrc[2];
            v0 = vsrc[0]; v1 = vsrc[1]; v2 = vsrc[2];
        }
        uint4* kd = (uint4*)(Ks + sp * PSTR);
        uint4* vd = (uint4*)(Vs + sp * PSTR);
        kd[0] = k0; kd[1] = k1; kd[2] = k2;
        vd[0] = v0; vd[1] = v1; vd[2] = v2;
    }
    __syncthreads();

    int ty = lane >> 3, tx = lane & 7;
    int gp = b * HW + (y0 + ty) * 64 + (x0 + tx);

    unsigned int q[12];
    {
        const uint4* qs = (const uint4*)(Qh + (size_t)gp * CC + h * D);
        uint4 a = qs[0], bb = qs[1], cq = qs[2];
        q[0]=a.x;  q[1]=a.y;  q[2]=a.z;  q[3]=a.w;
        q[4]=bb.x; q[5]=bb.y; q[6]=bb.z; q[7]=bb.w;
        q[8]=cq.x; q[9]=cq.y; q[10]=cq.z; q[11]=cq.w;
    }

    float acc[D];
    #pragma unroll
    for (int j = 0; j < D; ++j) acc[j] = 0.f;
    float l  = 0.f;
    int   cp = (ty + HALO) * SW + (tx + HALO);

    auto visit = [&](int di, int dj) {
        int sp = cp + di * SW + dj;
        const uint4* kp = (const uint4*)(Ks + sp * PSTR);
        uint4 k0 = kp[0], k1 = kp[1], k2 = kp[2];
        unsigned int ku[12] = {k0.x,k0.y,k0.z,k0.w, k1.x,k1.y,k1.z,k1.w, k2.x,k2.y,k2.z,k2.w};
        float s = 0.f;
        #pragma unroll
        for (int i = 0; i < 12; ++i) s = fdot2h(ku[i], q[i], s);
        float pw = __expf(s * INV_SCALE);
        l += pw;
        const uint4* vp = (const uint4*)(Vs + sp * PSTR);
        uint4 v0 = vp[0], v1 = vp[1], v2 = vp[2];
        unsigned int vu[12] = {v0.x,v0.y,v0.z,v0.w, v1.x,v1.y,v1.z,v1.w, v2.x,v2.y,v2.z,v2.w};
        #pragma unroll
        for (int i = 0; i < 12; ++i) {
            float2 f = __half22float2(__builtin_bit_cast(__half2, vu[i]));
            acc[2*i]   = fmaf(pw, f.x, acc[2*i]);
            acc[2*i+1] = fmaf(pw, f.y, acc[2*i+1]);
        }
    };

    if (wvid == 0) {
        #pragma unroll
        for (int k = 0; k < 49; k += 4) visit(k / 7 - 3, k % 7 - 3);
    } else if (wvid == 1) {
        #pragma unroll
        for (int k = 1; k < 49; k += 4) visit(k / 7 - 3, k % 7 - 3);
    } else if (wvid == 2) {
        #pragma unroll
        for (int k = 2; k < 49; k += 4) visit(k / 7 - 3, k % 7 - 3);
    } else if (wvid == 3) {
        #pragma unroll
        for (int k = 3; k < 49; k += 4) visit(k / 7 - 3, k % 7 - 3);
    } else if (wvid == 4) {
        #pragma unroll
        for (int dj = -4; dj <= 4; ++dj) visit(-4, dj);
        #pragma unroll
        for (int di = -3; di <= 3; ++di) visit(di, -4);
    } else if (wvid == 5) {
        #pragma unroll
        for (int dj = -4; dj <= 4; ++dj) visit(4, dj);
        #pragma unroll
        for (int di = -3; di <= 3; ++di) visit(di, 4);
    } else if (wvid == 6) {
        #pragma unroll
        for (int dj = -5; dj <= 5; ++dj) visit(-5, dj);
        #pragma unroll
        for (int di = -4; di <= 4; ++di) visit(di, -5);
    } else {
        #pragma unroll
        for (int dj = -5; dj <= 5; ++dj) visit(5, dj);
        #pragma unroll
        for (int di = -4; di <= 4; ++di) visit(di, 5);
    }

    __syncthreads();               // visits done; K/V dead -> alias Pb
    {
        float* pp = Pb + (wvid * 64 + lane) * PBS;
        pp[0] = l;
        #pragma unroll
        for (int i = 0; i < D; ++i) pp[1 + i] = acc[i];
    }
    __syncthreads();

    if (wvid < 3) {
        int N = (wvid == 0) ? 4 : (wvid == 1) ? 6 : 8;
        float L = 0.f;
        float a[D];
        #pragma unroll
        for (int i = 0; i < D; ++i) a[i] = 0.f;
        for (int s = 0; s < N; ++s) {
            const float* pp = Pb + (s * 64 + lane) * PBS;
            L += pp[0];
            #pragma unroll
            for (int i = 0; i < D; ++i) a[i] += pp[1 + i];
        }
        float rl = 1.0f / L;
        unsigned int u[12];
        #pragma unroll
        for (int i = 0; i < 12; ++i)
            u[i] = packh2(a[2 * i] * rl, a[2 * i + 1] * rl);
        uint4* dp = (uint4*)(att + (size_t)gp * C3 + h * 72 + wvid * D);
        dp[0] = make_uint4(u[0], u[1], u[2],  u[3]);
        dp[1] = make_uint4(u[4], u[5], u[6],  u[7]);
        dp[2] = make_uint4(u[8], u[9], u[10], u[11]);
    }
}

// proj for one 64-px group, 8 waves (12 outs each). smem >= 37440 B.
__device__ __forceinline__ void proj_group(
    int grp, int t, int wvid, int lane, int nthreads, char* smem,
    const u16* __restrict__ att, const unsigned int* __restrict__ wh,
    const float* __restrict__ bo, float* __restrict__ out)
{
    unsigned int* ab = (unsigned int*)smem;   // [144][65] u32
    int gp0 = grp * 64;

    const uint4* src = (const uint4*)(att + (size_t)gp0 * C3);
    for (int u = t; u < 2304; u += nthreads) {     // 64 px * 36 uint4
        uint4 v  = src[u];
        int px   = u / 36;
        int c20  = (u - px * 36) * 4;
        ab[(c20    ) * 65 + px] = v.x;
        ab[(c20 + 1) * 65 + px] = v.y;
        ab[(c20 + 2) * 65 + px] = v.z;
        ab[(c20 + 3) * 65 + px] = v.w;
    }
    __syncthreads();

    int o0 = wvid * 12;
    int gp = gp0 + lane;
    int b  = gp >> 12, p = gp & 4095;

    float acc[12];
    #pragma unroll
    for (int j = 0; j < 12; ++j) acc[j] = bo[o0 + j];

    #pragma unroll
    for (int cb = 0; cb < 9; ++cb) {
        unsigned int xp[16];
        #pragma unroll
        for (int i = 0; i < 16; ++i) xp[i] = ab[(cb * 16 + i) * 65 + lane];
        #pragma unroll
        for (int j = 0; j < 12; ++j) {
            const unsigned int* wr = wh + (o0 + j) * (C3 / 2) + cb * 16;
            #pragma unroll
            for (int i = 0; i < 16; ++i) acc[j] = fdot2h(xp[i], wr[i], acc[j]);
        }
    }

    #pragma unroll
    for (int j = 0; j < 12; ++j)
        out[(size_t)(b * CC + o0 + j) * HW + p] = acc[j];
}

// ======================= cooperative fused kernel (256 blocks) ==============

__global__ __launch_bounds__(512, 2) void fused_kernel(
    const float* __restrict__ x,
    const float* __restrict__ wq, const float* __restrict__ bq,
    const float* __restrict__ wk, const float* __restrict__ bk,
    const float* __restrict__ wv, const float* __restrict__ bv,
    const float* __restrict__ wo, const float* __restrict__ bo,
    u16* __restrict__ Qh, u16* __restrict__ Kh, u16* __restrict__ Vh,
    u16* __restrict__ att, unsigned int* __restrict__ wh,
    float* __restrict__ out)
{
    cg::grid_group grid = cg::this_grid();
    __shared__ __align__(16) char smem[51200];

    const int t    = threadIdx.x;
    const int blk  = blockIdx.x;
    const int wvid = __builtin_amdgcn_readfirstlane(t >> 6);
    const int lane = t & 63;

    // phase 0: pack wo -> wh (13824 u32)
    {
        int idx = blk * 512 + t;
        if (idx < CC * (C3 / 2)) {
            int o  = idx / (C3 / 2);
            int c2 = idx - o * (C3 / 2);
            wh[idx] = packh2(wo[o * C3 + 2 * c2], wo[o * C3 + 2 * c2 + 1]);
        }
    }

    // phase 1: QKV — 3072 wave-tasks over 2048 waves
    {
        int wave_gid = blk * 8 + wvid;
        for (int task = wave_gid; task < 3072; task += 2048)
            qkv_wave_task(task, lane, x, wq, bq, wk, bk, wv, bv, Qh, Kh, Vh);
    }

    grid.sync();

    // phase 2: attention — 512 tiles, 2 per block
    #pragma unroll
    for (int tt = 0; tt < 2; ++tt) {
        attn_tile(blk * 2 + tt, t, wvid, lane, smem, Qh, Kh, Vh, att);
        __syncthreads();   // protect LDS reuse across iterations / phase 3
    }

    grid.sync();

    // phase 3: projection — 128 groups of 64 px
    if (blk < 128)
        proj_group(blk, t, wvid, lane, 512, smem, att, wh, bo, out);
}

// ======================= fallback kernels (proven round-3 path) =============

__global__ void prep_w(const float* __restrict__ wo, unsigned int* __restrict__ wh) {
    int idx = blockIdx.x * 256 + threadIdx.x;
    if (idx < CC * (C3 / 2)) {
        int o  = idx / (C3 / 2);
        int c2 = idx - o * (C3 / 2);
        wh[idx] = packh2(wo[o * C3 + 2 * c2], wo[o * C3 + 2 * c2 + 1]);
    }
}

__global__ __launch_bounds__(256) void qkv_kernel(
    const float* __restrict__ x,
    const float* __restrict__ wq, const float* __restrict__ bq,
    const float* __restrict__ wk, const float* __restrict__ bk,
    const float* __restrict__ wv, const float* __restrict__ bv,
    u16* __restrict__ Qh, u16* __restrict__ Kh, u16* __restrict__ Vh)
{
    int t = threadIdx.x;
    // task = zm*512 + pxg*4 + tw mapped from (blockIdx.x, blockIdx.y, wave)
    int task = (blockIdx.y * 128 + blockIdx.x) * 4 + (t >> 6);
    qkv_wave_task(task, t & 63, x, wq, bq, wk, bk, wv, bv, Qh, Kh, Vh);
}

__global__ __launch_bounds__(512) void attn_kernel(
    const u16* __restrict__ Qh, const u16* __restrict__ Kh,
    const u16* __restrict__ Vh, u16* __restrict__ att)
{
    __shared__ __align__(16) char smem[51200];
    int t = threadIdx.x;
    attn_tile(blockIdx.x, t, __builtin_amdgcn_readfirstlane(t >> 6), t & 63,
              smem, Qh, Kh, Vh, att);
}

__global__ __launch_bounds__(512) void proj_kernel(
    const u16* __restrict__ att, const unsigned int* __restrict__ wh,
    const float* __restrict__ bo, float* __restrict__ out)
{
    __shared__ __align__(16) char smem[37440];
    int t = threadIdx.x;
    proj_group(blockIdx.x, t, __builtin_amdgcn_readfirstlane(t >> 6), t & 63,
               512, smem, att, wh, bo, out);
}

// ======================= launch =============================================

extern "C" void kernel_launch(void* const* d_in, const int* in_sizes, int n_in,
                              void* d_out, int out_size, void* d_ws, size_t ws_size,
                              hipStream_t stream)
{
    const float* x  = (const float*)d_in[0];
    const float* wq = (const float*)d_in[1];
    const float* bq = (const float*)d_in[2];
    const float* wk = (const float*)d_in[3];
    const float* bk = (const float*)d_in[4];
    const float* wv = (const float*)d_in[5];
    const float* bv = (const float*)d_in[6];
    const float* wo = (const float*)d_in[7];
    const float* bo = (const float*)d_in[8];
    float* out = (float*)d_out;

    const size_t NPIX = (size_t)BATCH * HW;     // 8192
    char* ws = (char*)d_ws;
    u16* Qh  = (u16*)ws;
    u16* Kh  = Qh + NPIX * CC;
    u16* Vh  = Kh + NPIX * CC;
    u16* att = Vh + NPIX * CC;
    unsigned int* wh = (unsigned int*)(att + NPIX * C3);

    void* args[] = {
        (void*)&x, (void*)&wq, (void*)&bq, (void*)&wk, (void*)&bk,
        (void*)&wv, (void*)&bv, (void*)&wo, (void*)&bo,
        (void*)&Qh, (void*)&Kh, (void*)&Vh, (void*)&att, (void*)&wh,
        (void*)&out
    };
    hipError_t err = hipLaunchCooperativeKernel((const void*)fused_kernel,
                                                dim3(256), dim3(512), args, 0, stream);
    if (err != hipSuccess) {
        // fallback: proven 4-dispatch path
        prep_w<<<dim3(54), 256, 0, stream>>>(wo, wh);
        qkv_kernel<<<dim3(128, 6), 256, 0, stream>>>(x, wq, bq, wk, bk, wv, bv,
                                                     Qh, Kh, Vh);
        attn_kernel<<<dim3(512), 512, 0, stream>>>(Qh, Kh, Vh, att);
        proj_kernel<<<dim3(128), 512, 0, stream>>>(att, wh, bo, out);
    }
}

// Round 6
// 127.359 us; speedup vs baseline: 1.9066x; 1.9066x over previous
//
#include <hip/hip_runtime.h>
#include <hip/hip_fp16.h>

// DenseMultiRangeAttention on MI355X (gfx950) — round 6: I$-resident kernels
// (roll all hot loops; ~2-4KB code each). 3 dispatches.
// B=2, C=96, H=W=64, heads=4, d=24, ranges {7,9,11}
//
//   K1 qkv_pack : by<6 -> QKV (f32 GEMV, rolled); by==6 -> pack wo->wh f16x2
//   K2 attn     : 512 blocks x 8 waves; rolled visit loops, wave-uniform
//                 (di,dj) from runtime k; LDS partial combine; ranges 7/9/11
//   K3 proj     : (128,4) x 256; 6 outs/wave; att tile [144][65] u32 in LDS

#define HW    4096
#define NH    4
#define D     24
#define CC    96
#define C3    288
#define BATCH 2

#define TS    8
#define HALO  5
#define SW    18
#define SPIX  324      // SW*SW
#define PSTR  24       // u16 per staged K/V pixel = 48B
#define PBS   25       // partial stride (f32): l + 24 acc; gcd(25,32)=1

#define INV_SCALE 0.20412414523193151f  // 1/sqrt(24)

typedef unsigned short u16;
typedef _Float16 h2f __attribute__((ext_vector_type(2)));

__device__ __forceinline__ float fdot2h(unsigned int a, unsigned int b, float c) {
#if __has_builtin(__builtin_amdgcn_fdot2)
    return __builtin_amdgcn_fdot2(__builtin_bit_cast(h2f, a),
                                  __builtin_bit_cast(h2f, b), c, false);
#else
    float2 fa = __half22float2(__builtin_bit_cast(__half2, a));
    float2 fb = __half22float2(__builtin_bit_cast(__half2, b));
    return fmaf(fa.x, fb.x, fmaf(fa.y, fb.y, c));
#endif
}

__device__ __forceinline__ unsigned int packh2(float a, float b) {
    return __builtin_bit_cast(unsigned int, __floats2half2_rn(a, b));
}

// ---------------------------------------------------------------- K1
// grid (128, 7) block 256.
// by<6: QKV. mat = by%3, z = by/3. Wave: 12 outs (o0 = z*48 + wvid*12) for
// 64 px. x read direct (L2/LLC-resident); cb loop ROLLED (I$).
// by==6, bx<54: pack wo (96x288 f32) -> wh (96x144 u32 f16-pairs).
__global__ __launch_bounds__(256) void qkv_pack_kernel(
    const float* __restrict__ x,
    const float* __restrict__ wq, const float* __restrict__ bq,
    const float* __restrict__ wk, const float* __restrict__ bk,
    const float* __restrict__ wv, const float* __restrict__ bv,
    const float* __restrict__ wo,
    u16* __restrict__ Qh, u16* __restrict__ Kh, u16* __restrict__ Vh,
    unsigned int* __restrict__ wh)
{
    int t  = threadIdx.x;
    int by = blockIdx.y;

    if (by == 6) {                       // ---- pack wo
        int idx = blockIdx.x * 256 + t;  // bx<54 covers 13824
        if (blockIdx.x < 54) {
            int o  = idx / (C3 / 2);
            int c2 = idx - o * (C3 / 2);
            wh[idx] = packh2(wo[o * C3 + 2 * c2], wo[o * C3 + 2 * c2 + 1]);
        }
        return;
    }

    int mat = by % 3, z = by / 3;
    const float* w    = (mat == 0) ? wq : (mat == 1) ? wk : wv;
    const float* bias = (mat == 0) ? bq : (mat == 1) ? bk : bv;
    u16* dst          = (mat == 0) ? Qh : (mat == 1) ? Kh : Vh;

    int gp = blockIdx.x * 64 + (t & 63);
    int b  = gp >> 12;
    int p  = gp & 4095;
    int o0 = z * 48 + __builtin_amdgcn_readfirstlane(t >> 6) * 12;

    const float* xb = x + (size_t)b * CC * HW + p;

    float acc[12];
    #pragma unroll
    for (int j = 0; j < 12; ++j) acc[j] = bias[o0 + j];

    #pragma unroll 2                       // rolled: keep code ~3KB
    for (int cb = 0; cb < 6; ++cb) {
        float xc[16];
        #pragma unroll
        for (int i = 0; i < 16; ++i)
            xc[i] = xb[(size_t)(cb * 16 + i) * HW];
        #pragma unroll
        for (int j = 0; j < 12; ++j) {
            const float* wr = w + (o0 + j) * CC + cb * 16;
            #pragma unroll
            for (int i = 0; i < 16; ++i) acc[j] = fmaf(wr[i], xc[i], acc[j]);
        }
    }

    unsigned int u[6];
    #pragma unroll
    for (int i = 0; i < 6; ++i) u[i] = packh2(acc[2 * i], acc[2 * i + 1]);
    uint2* dp = (uint2*)(dst + (size_t)gp * CC + o0);
    dp[0] = make_uint2(u[0], u[1]);
    dp[1] = make_uint2(u[2], u[3]);
    dp[2] = make_uint2(u[4], u[5]);
}

// ---------------------------------------------------------------- K2
// grid 512 block 512 (8 waves). blk = tilex(3b) | tiley(3b) | bh(3b).
// Visit split (all k wave-uniform -> scalar addressing, uniform branches):
//   waves 0-3: core 7x7, k = wvid + 4i (13/12/12/12)
//   waves 4-5: ring->9,  j = (wvid-4) + 2i, 16 each
//   waves 6-7: ring->11, j = (wvid-6) + 2i, 20 each
// Rolled loops: hot code ~2KB (I$-resident). Partials combined via LDS.
__global__ __launch_bounds__(512) void attn_kernel(
    const u16* __restrict__ Qh, const u16* __restrict__ Kh,
    const u16* __restrict__ Vh, u16* __restrict__ att)
{
    __shared__ __align__(16) char smem[51200];
    u16*   Ks = (u16*)smem;                 // 324*24*2 = 15552 B
    u16*   Vs = Ks + SPIX * PSTR;           // 15552 B
    float* Pb = (float*)smem;               // aliased after visit phase

    int t    = threadIdx.x;
    int wvid = __builtin_amdgcn_readfirstlane(t >> 6);
    int lane = t & 63;
    int blk  = blockIdx.x;
    int bh   = blk >> 6;
    int b    = bh >> 2, h = bh & 3;
    int x0   = (blk & 7) * TS, y0 = ((blk >> 3) & 7) * TS;

    // stage K,V tile (+halo), zeros outside image (== reference zero-pad)
    if (t < SPIX) {
        int sp = t;
        int sy = sp / SW, sx = sp - sy * SW;
        int gy = y0 + sy - HALO, gx = x0 + sx - HALO;
        uint4 k0 = make_uint4(0,0,0,0), k1 = k0, k2 = k0;
        uint4 v0 = k0, v1 = k0, v2 = k0;
        if ((unsigned)gy < 64u && (unsigned)gx < 64u) {
            size_t base = ((size_t)(b * HW + gy * 64 + gx) * CC + h * D);
            const uint4* ksrc = (const uint4*)(Kh + base);
            const uint4* vsrc = (const uint4*)(Vh + base);
            k0 = ksrc[0]; k1 = ksrc[1]; k2 = ksrc[2];
            v0 = vsrc[0]; v1 = vsrc[1]; v2 = vsrc[2];
        }
        uint4* kd = (uint4*)(Ks + sp * PSTR);
        uint4* vd = (uint4*)(Vs + sp * PSTR);
        kd[0] = k0; kd[1] = k1; kd[2] = k2;
        vd[0] = v0; vd[1] = v1; vd[2] = v2;
    }
    __syncthreads();

    int ty = lane >> 3, tx = lane & 7;
    int gp = b * HW + (y0 + ty) * 64 + (x0 + tx);

    unsigned int q[12];
    {
        const uint4* qs = (const uint4*)(Qh + (size_t)gp * CC + h * D);
        uint4 a = qs[0], bb = qs[1], cq = qs[2];
        q[0]=a.x;  q[1]=a.y;  q[2]=a.z;  q[3]=a.w;
        q[4]=bb.x; q[5]=bb.y; q[6]=bb.z; q[7]=bb.w;
        q[8]=cq.x; q[9]=cq.y; q[10]=cq.z; q[11]=cq.w;
    }

    float acc[D];
    #pragma unroll
    for (int j = 0; j < D; ++j) acc[j] = 0.f;
    float l  = 0.f;
    int   cp = (ty + HALO) * SW + (tx + HALO);

    auto visit = [&](int di, int dj) {
        int sp = cp + di * SW + dj;
        const uint4* kp = (const uint4*)(Ks + sp * PSTR);
        uint4 k0 = kp[0], k1 = kp[1], k2 = kp[2];
        unsigned int ku[12] = {k0.x,k0.y,k0.z,k0.w, k1.x,k1.y,k1.z,k1.w, k2.x,k2.y,k2.z,k2.w};
        float s = 0.f;
        #pragma unroll
        for (int i = 0; i < 12; ++i) s = fdot2h(ku[i], q[i], s);
        float pw = __expf(s * INV_SCALE);
        l += pw;
        const uint4* vp = (const uint4*)(Vs + sp * PSTR);
        uint4 v0 = vp[0], v1 = vp[1], v2 = vp[2];
        unsigned int vu[12] = {v0.x,v0.y,v0.z,v0.w, v1.x,v1.y,v1.z,v1.w, v2.x,v2.y,v2.z,v2.w};
        #pragma unroll
        for (int i = 0; i < 12; ++i) {
            float2 f = __half22float2(__builtin_bit_cast(__half2, vu[i]));
            acc[2*i]   = fmaf(pw, f.x, acc[2*i]);
            acc[2*i+1] = fmaf(pw, f.y, acc[2*i+1]);
        }
    };

    if (wvid < 4) {
        for (int k = wvid; k < 49; k += 4) {        // core 7x7
            int di = k / 7 - 3;
            int dj = k - (di + 3) * 7 - 3;
            visit(di, dj);
        }
    } else if (wvid < 6) {
        for (int j = wvid - 4; j < 32; j += 2) {    // ring 9x9 \ 7x7
            int di = (j < 9)  ? -4 : (j < 18) ? 4 : (j < 25) ? j - 21 : j - 28;
            int dj = (j < 9)  ? j - 4 : (j < 18) ? j - 13 : (j < 25) ? -4 : 4;
            visit(di, dj);
        }
    } else {
        for (int j = wvid - 6; j < 40; j += 2) {    // ring 11x11 \ 9x9
            int di = (j < 11) ? -5 : (j < 22) ? 5 : (j < 31) ? j - 26 : j - 35;
            int dj = (j < 11) ? j - 5 : (j < 22) ? j - 16 : (j < 31) ? -5 : 5;
            visit(di, dj);
        }
    }

    __syncthreads();               // visits done; K/V dead -> alias Pb
    {
        float* pp = Pb + (wvid * 64 + lane) * PBS;
        pp[0] = l;
        #pragma unroll
        for (int i = 0; i < D; ++i) pp[1 + i] = acc[i];
    }
    __syncthreads();

    // wave r in {0,1,2}: range r = sum of partials {0..3}, {0..5}, {0..7}
    if (wvid < 3) {
        int N = (wvid == 0) ? 4 : (wvid == 1) ? 6 : 8;
        float L = 0.f;
        float a[D];
        #pragma unroll
        for (int i = 0; i < D; ++i) a[i] = 0.f;
        for (int s = 0; s < N; ++s) {
            const float* pp = Pb + (s * 64 + lane) * PBS;
            L += pp[0];
            #pragma unroll
            for (int i = 0; i < D; ++i) a[i] += pp[1 + i];
        }
        float rl = 1.0f / L;
        unsigned int u[12];
        #pragma unroll
        for (int i = 0; i < 12; ++i)
            u[i] = packh2(a[2 * i] * rl, a[2 * i + 1] * rl);
        uint4* dp = (uint4*)(att + (size_t)gp * C3 + h * 72 + wvid * D);
        dp[0] = make_uint4(u[0], u[1], u[2],  u[3]);
        dp[1] = make_uint4(u[4], u[5], u[6],  u[7]);
        dp[2] = make_uint4(u[8], u[9], u[10], u[11]);
    }
}

// ---------------------------------------------------------------- K3
// grid (128, 4) block 256 (4 waves). Block: 64 px, 24 outs (6/wave,
// o0 = by*24 + wvid*6). att tile staged [144][65] u32; cb loop ROLLED.
#define K3_PAD 65
__global__ __launch_bounds__(256) void proj_kernel(
    const u16* __restrict__ att, const unsigned int* __restrict__ wh,
    const float* __restrict__ bo, float* __restrict__ out)
{
    __shared__ unsigned int ab[(C3 / 2) * K3_PAD];   // 37440 B

    int t   = threadIdx.x;
    int gp0 = blockIdx.x * 64;

    const uint4* src = (const uint4*)(att + (size_t)gp0 * C3);
    for (int u = t; u < 2304; u += 256) {     // 64 px * 36 uint4
        uint4 v  = src[u];
        int px   = u / 36;
        int c20  = (u - px * 36) * 4;
        ab[(c20    ) * K3_PAD + px] = v.x;
        ab[(c20 + 1) * K3_PAD + px] = v.y;
        ab[(c20 + 2) * K3_PAD + px] = v.z;
        ab[(c20 + 3) * K3_PAD + px] = v.w;
    }
    __syncthreads();

    int wvid = __builtin_amdgcn_readfirstlane(t >> 6);
    int lane = t & 63;
    int o0   = blockIdx.y * 24 + wvid * 6;
    int gp   = gp0 + lane;
    int b    = gp >> 12, p = gp & 4095;

    float acc[6];
    #pragma unroll
    for (int j = 0; j < 6; ++j) acc[j] = bo[o0 + j];

    #pragma unroll 1                          // rolled: keep code small
    for (int cb = 0; cb < 9; ++cb) {
        unsigned int xp[16];
        #pragma unroll
        for (int i = 0; i < 16; ++i) xp[i] = ab[(cb * 16 + i) * K3_PAD + lane];
        #pragma unroll
        for (int j = 0; j < 6; ++j) {
            const unsigned int* wr = wh + (o0 + j) * (C3 / 2) + cb * 16;
            #pragma unroll
            for (int i = 0; i < 16; ++i) acc[j] = fdot2h(xp[i], wr[i], acc[j]);
        }
    }

    #pragma unroll
    for (int j = 0; j < 6; ++j)
        out[(size_t)(b * CC + o0 + j) * HW + p] = acc[j];
}

// ---------------------------------------------------------------- launch
extern "C" void kernel_launch(void* const* d_in, const int* in_sizes, int n_in,
                              void* d_out, int out_size, void* d_ws, size_t ws_size,
                              hipStream_t stream)
{
    const float* x  = (const float*)d_in[0];
    const float* wq = (const float*)d_in[1];
    const float* bq = (const float*)d_in[2];
    const float* wk = (const float*)d_in[3];
    const float* bk = (const float*)d_in[4];
    const float* wv = (const float*)d_in[5];
    const float* bv = (const float*)d_in[6];
    const float* wo = (const float*)d_in[7];
    const float* bo = (const float*)d_in[8];
    float* out = (float*)d_out;

    const size_t NPIX = (size_t)BATCH * HW;     // 8192
    char* ws = (char*)d_ws;
    u16* Qh  = (u16*)ws;                        // 1.5 MB
    u16* Kh  = Qh + NPIX * CC;
    u16* Vh  = Kh + NPIX * CC;
    u16* att = Vh + NPIX * CC;                  // 4.7 MB
    unsigned int* wh = (unsigned int*)(att + NPIX * C3);  // 55 KB

    qkv_pack_kernel<<<dim3(128, 7), 256, 0, stream>>>(
        x, wq, bq, wk, bk, wv, bv, wo, Qh, Kh, Vh, wh);

    attn_kernel<<<dim3(512), 512, 0, stream>>>(Qh, Kh, Vh, att);

    proj_kernel<<<dim3(128, 4), 256, 0, stream>>>(att, wh, bo, out);
}